// Round 9
// baseline (165.502 us; speedup 1.0000x reference)
//
#include <hip/hip_runtime.h>
#include <cstdint>
#include <cstddef>

#define EMBED 1024
#define HEAD  128
#define BATCH 4
#define SEQ   4096
#define KSC   0.04508422f   // log2(e)/sqrt(1024)

typedef __attribute__((ext_vector_type(4))) float f32x4;
typedef __attribute__((ext_vector_type(16))) float f32x16;
typedef __attribute__((ext_vector_type(8))) short s16x8;
typedef __attribute__((ext_vector_type(4))) int i32x4;
typedef __attribute__((ext_vector_type(4))) unsigned short u16x4;

__device__ __forceinline__ unsigned short f2bf(float f) {
    union { float f; unsigned u; } v; v.f = f;
    unsigned r = v.u + 0x7fffu + ((v.u >> 16) & 1u);
    return (unsigned short)(r >> 16);
}

__device__ __forceinline__ int cvtpk(float lo, float hi_) {
    int r;
    asm("v_cvt_pk_bf16_f32 %0, %1, %2" : "=v"(r) : "v"(lo), "v"(hi_));
    return r;
}

// async 16B global->LDS (per-lane global src; LDS dest = wave base + lane*16)
__device__ __forceinline__ void gload16(const void* g, void* l) {
    __builtin_amdgcn_global_load_lds(
        (const __attribute__((address_space(1))) unsigned int*)g,
        (__attribute__((address_space(3))) unsigned int*)l, 16, 0, 0);
}

// ---- W [1024][128] f32 x3 -> Wt bf16 PRE-SWIZZLED for proj's global_load_lds:
// layout [sel][kb=16 blocks of 64k][h=128][phys_slot=8 x 16B], where
// phys = slot ^ (h&7), slot = 8-elem k-chunk within the 64-k block. (T21)
__global__ __launch_bounds__(256) void wt_kernel(const float* __restrict__ Wq,
                                                 const float* __restrict__ Wk,
                                                 const float* __restrict__ Wv,
                                                 unsigned short* __restrict__ Wt) {
    __shared__ __align__(16) float Lw[64 * 132];
    const int tid = threadIdx.x;
    const int sel = blockIdx.x >> 4;
    const int kb  = blockIdx.x & 15;
    const int k0  = kb * 64;
    const float* W = (sel == 0) ? Wq : (sel == 1) ? Wk : Wv;
    #pragma unroll
    for (int it = 0; it < 8; ++it) {
        int c = tid + it * 256;                   // 2048 f32x4 chunks
        int kk = c >> 5, hc = c & 31;
        *(f32x4*)&Lw[kk * 132 + hc * 4] =
            *(const f32x4*)(W + (size_t)(k0 + kk) * HEAD + hc * 4);
    }
    __syncthreads();
    #pragma unroll
    for (int it = 0; it < 4; ++it) {
        int c = tid + it * 256;                   // 1024 16B chunks
        int h = c >> 3, sl = c & 7;
        int phys = sl ^ (h & 7);
        int p0 = cvtpk(Lw[(sl * 8 + 0) * 132 + h], Lw[(sl * 8 + 1) * 132 + h]);
        int p1 = cvtpk(Lw[(sl * 8 + 2) * 132 + h], Lw[(sl * 8 + 3) * 132 + h]);
        int p2 = cvtpk(Lw[(sl * 8 + 4) * 132 + h], Lw[(sl * 8 + 5) * 132 + h]);
        int p3 = cvtpk(Lw[(sl * 8 + 6) * 132 + h], Lw[(sl * 8 + 7) * 132 + h]);
        i32x4 pk = {p0, p1, p2, p3};
        *(s16x8*)(Wt + (size_t)sel * 131072 + kb * 8192 + h * 64 + phys * 8) = *(s16x8*)&pk;
    }
}

// ---- projection GEMM: grid (256, 3), tile 64x128, BK=64, 4 waves (2x2).
// B-tile staged via global_load_lds (pre-swizzled Wt -> linear LDS, XOR reads).
// sel0: Q (pre-scaled KSC), sel1: K, sel2: V transposed (Vt [B][128][T]).
__global__ __launch_bounds__(256) void proj_kernel(const float* __restrict__ ctx,
                                                   const unsigned short* __restrict__ Wt,
                                                   unsigned short* __restrict__ Qb,
                                                   unsigned short* __restrict__ Kb,
                                                   unsigned short* __restrict__ Vtb) {
    __shared__ __align__(16) short As[64 * 72];   // reg-staged (fp32->bf16), padded
    __shared__ __align__(16) short Bs[128 * 64];  // gload_lds dest, swizzled image
    const int tid = threadIdx.x;
    const int lane = tid & 63, w = tid >> 6;
    const int wr = w >> 1, wc = w & 1;
    const int lr = lane & 15, lk = lane >> 4;
    const int m0 = blockIdx.x * 64;
    const int sel = blockIdx.y;
    const unsigned short* Wts = Wt + (size_t)sel * 131072;

    f32x4 zero = {0.f, 0.f, 0.f, 0.f};
    f32x4 acc[2][4];
    #pragma unroll
    for (int i = 0; i < 2; ++i)
        #pragma unroll
        for (int jn = 0; jn < 4; ++jn) acc[i][jn] = zero;

    for (int kkb = 0; kkb < 16; ++kkb) {
        __syncthreads();
        // B: 16KB via 16 gload_lds (4 per wave), linear copy of swizzled image
        const char* gb = (const char*)Wts + kkb * 16384;
        #pragma unroll
        for (int i = 0; i < 4; ++i) {
            int chunk = w * 4 + i;
            gload16(gb + chunk * 1024 + lane * 16, (char*)Bs + chunk * 1024);
        }
        // A: 64 rows x 64 k fp32 -> bf16 via v_cvt_pk (2 chunks/thread)
        const int kk = kkb * 64;
        #pragma unroll
        for (int t = 0; t < 2; ++t) {
            int c = tid + t * 256;
            int row = c >> 3, cg = c & 7;
            const float* src = ctx + (size_t)(m0 + row) * EMBED + kk + cg * 8;
            f32x4 x0 = *(const f32x4*)src;
            f32x4 x1 = *(const f32x4*)(src + 4);
            int p0 = cvtpk(x0[0], x0[1]);
            int p1 = cvtpk(x0[2], x0[3]);
            int p2 = cvtpk(x1[0], x1[1]);
            int p3 = cvtpk(x1[2], x1[3]);
            i32x4 pk = {p0, p1, p2, p3};
            *(s16x8*)&As[row * 72 + cg * 8] = *(s16x8*)&pk;
        }
        __syncthreads();
        s16x8 af[2][2], bfr[4][2];
        #pragma unroll
        for (int mi = 0; mi < 2; ++mi)
            #pragma unroll
            for (int k2 = 0; k2 < 2; ++k2)
                af[mi][k2] = *(const s16x8*)&As[(wr * 32 + mi * 16 + lr) * 72 + k2 * 32 + lk * 8];
        #pragma unroll
        for (int ni = 0; ni < 4; ++ni)
            #pragma unroll
            for (int k2 = 0; k2 < 2; ++k2) {
                int rB = wc * 64 + ni * 16 + lr;
                int phys = (k2 * 4 + lk) ^ (rB & 7);
                bfr[ni][k2] = *(const s16x8*)((const char*)Bs + rB * 128 + phys * 16);
            }
        #pragma unroll
        for (int k2 = 0; k2 < 2; ++k2)
            #pragma unroll
            for (int mi = 0; mi < 2; ++mi)
                #pragma unroll
                for (int ni = 0; ni < 4; ++ni)
                    acc[mi][ni] = __builtin_amdgcn_mfma_f32_16x16x32_bf16(af[mi][k2], bfr[ni][k2], acc[mi][ni], 0, 0, 0);
    }

    if (sel == 2) {
        #pragma unroll
        for (int mi = 0; mi < 2; ++mi) {
            int t0r = m0 + wr * 32 + mi * 16 + lk * 4;
            int b = t0r >> 12, tl = t0r & (SEQ - 1);
            #pragma unroll
            for (int ni = 0; ni < 4; ++ni) {
                int col = wc * 64 + ni * 16 + lr;
                u16x4 vv;
                #pragma unroll
                for (int r = 0; r < 4; ++r) vv[r] = f2bf(acc[mi][ni][r]);
                *(u16x4*)(Vtb + ((size_t)(b * HEAD + col)) * SEQ + tl) = vv;
            }
        }
    } else {
        unsigned short* outp = sel ? Kb : Qb;
        const float sc = sel ? 1.0f : KSC;
        #pragma unroll
        for (int mi = 0; mi < 2; ++mi) {
            int row = m0 + wr * 32 + mi * 16 + lk * 4;
            #pragma unroll
            for (int ni = 0; ni < 4; ++ni) {
                int col = wc * 64 + ni * 16 + lr;
                #pragma unroll
                for (int r = 0; r < 4; ++r)
                    outp[(size_t)(row + r) * HEAD + col] = f2bf(acc[mi][ni][r] * sc);
            }
        }
    }
}

// ---- flash attention: 4 waves x 32 q-rows, 32x32x16 MFMA, swapped QK^T,
// in-register softmax (Q pre-scaled), KV chunks of 256 keys, single-buffered
// 32KB LDS, T14 early-issue loads, LDS-repacked coalesced epilogue.
__global__ __launch_bounds__(256, 2) void attn_kernel(const unsigned short* __restrict__ Q,
                                                      const unsigned short* __restrict__ K,
                                                      const unsigned short* __restrict__ Vt,
                                                      unsigned short* __restrict__ po,
                                                      float* __restrict__ pml) {
    __shared__ __align__(16) char smem[32768];   // K 16KB + Vt 16KB, XOR-swizzled
    const int tid = threadIdx.x;
    const int lane = tid & 63, w = tid >> 6;
    const int l31 = lane & 31, hi = lane >> 5;
    const int hi16 = hi << 4;

    const int b = blockIdx.x / 272;
    int t = blockIdx.x % 272;
    int qt = 0, cum = 0;
    while (cum + ((qt >> 1) + 1) <= t) { cum += (qt >> 1) + 1; ++qt; }
    const int c = t - cum;
    const int nj = min(4, 2 * qt + 2 - 4 * c);
    const int kb0 = c * 256;
    const int slot = b * 272 + cum + c;

    const unsigned short* qp = Q + ((size_t)(b * SEQ + qt * 128 + w * 32 + l31)) * HEAD + hi * 8;
    s16x8 qf[8];
    #pragma unroll
    for (int dt = 0; dt < 8; ++dt) qf[dt] = *(const s16x8*)(qp + dt * 16);

    f32x16 o0, o1, o2, o3;
    #pragma unroll
    for (int r = 0; r < 16; ++r) { o0[r] = 0.f; o1[r] = 0.f; o2[r] = 0.f; o3[r] = 0.f; }
    float m_run = -1e30f, l_run = 0.f;

    const int krow = tid >> 4, kch = tid & 15;
    const int vdr  = tid >> 3, vch = tid & 7;

    s16x8 kst[4], vst[4];
    #pragma unroll
    for (int p = 0; p < 4; ++p) {
        kst[p] = *(const s16x8*)(K + ((size_t)(b * SEQ + kb0 + krow + p * 16)) * HEAD + kch * 8);
        vst[p] = *(const s16x8*)(Vt + ((size_t)(b * HEAD + vdr + p * 32)) * SEQ + kb0 + vch * 8);
    }
    #pragma unroll
    for (int p = 0; p < 4; ++p) {
        int r0 = krow + p * 16;
        *(s16x8*)(smem + r0 * 256 + ((kch * 16) ^ ((r0 & 7) << 4))) = kst[p];
        int d0 = vdr + p * 32;
        *(s16x8*)(smem + 16384 + d0 * 128 + ((vch * 16) ^ ((d0 & 7) << 4))) = vst[p];
    }
    __syncthreads();

    for (int j = 0; j < nj; ++j) {
        const int kb = kb0 + j * 64;
        if (j + 1 < nj) {                        // early-issue next-tile loads (T14)
            int kbn = kb + 64;
            #pragma unroll
            for (int p = 0; p < 4; ++p) {
                kst[p] = *(const s16x8*)(K + ((size_t)(b * SEQ + kbn + krow + p * 16)) * HEAD + kch * 8);
                vst[p] = *(const s16x8*)(Vt + ((size_t)(b * HEAD + vdr + p * 32)) * SEQ + kbn + vch * 8);
            }
        }

        // ---- QK^T swapped: st[t][r] = S_log2[k = 32t + crow(r,hi)][q = l31]
        f32x16 st0, st1;
        #pragma unroll
        for (int r = 0; r < 16; ++r) { st0[r] = 0.f; st1[r] = 0.f; }
        const int sw = (l31 & 7) << 4;
        const char* kbase0 = smem + l31 * 256;
        const char* kbase1 = kbase0 + 32 * 256;
        __builtin_amdgcn_s_setprio(1);
        #pragma unroll
        for (int dt = 0; dt < 8; ++dt) {
            s16x8 ka0 = *(const s16x8*)(kbase0 + ((dt * 32 + hi16) ^ sw));
            s16x8 ka1 = *(const s16x8*)(kbase1 + ((dt * 32 + hi16) ^ sw));
            st0 = __builtin_amdgcn_mfma_f32_32x32x16_bf16(ka0, qf[dt], st0, 0, 0, 0);
            st1 = __builtin_amdgcn_mfma_f32_32x32x16_bf16(ka1, qf[dt], st1, 0, 0, 0);
        }
        __builtin_amdgcn_s_setprio(0);

        // ---- causal mask (diagonal tiles only)
        if (4 * c + j >= 2 * qt) {
            const int qg = qt * 128 + w * 32 + l31;
            #pragma unroll
            for (int r = 0; r < 16; ++r) {
                int crow = (r & 3) + 8 * (r >> 2) + 4 * hi;
                if (kb + crow > qg)      st0[r] = -3e37f;
                if (kb + 32 + crow > qg) st1[r] = -3e37f;
            }
        }

        // ---- online softmax, fully in-register
        float mx = st0[0];
        #pragma unroll
        for (int r = 1; r < 16; ++r) mx = fmaxf(mx, st0[r]);
        #pragma unroll
        for (int r = 0; r < 16; ++r) mx = fmaxf(mx, st1[r]);
        mx = fmaxf(mx, __shfl_xor(mx, 32));
        if (!__all(mx <= m_run + 8.0f)) {        // defer-max (T13)
            float mn = fmaxf(m_run, mx);
            float f = exp2f(m_run - mn);
            l_run *= f;
            int fi = __float_as_int(f);
            #pragma unroll
            for (int r = 0; r < 16; ++r) {
                int srcb = 4 * ((r & 3) + 8 * (r >> 2)) + 16 * hi;
                float fr = __int_as_float(__builtin_amdgcn_ds_bpermute(srcb, fi));
                o0[r] *= fr; o1[r] *= fr; o2[r] *= fr; o3[r] *= fr;
            }
            m_run = mn;
        }
        float rs = 0.f;
        #pragma unroll
        for (int r = 0; r < 16; ++r) {
            st0[r] = exp2f(st0[r] - m_run); rs += st0[r];
            st1[r] = exp2f(st1[r] - m_run); rs += st1[r];
        }
        rs += __shfl_xor(rs, 32);
        l_run += rs;

        // ---- P -> bf16 PV A-frags in-register (T12)
        int a0 = cvtpk(st0[0], st0[1]),   b0 = cvtpk(st0[4], st0[5]);
        int a1 = cvtpk(st0[2], st0[3]),   b1 = cvtpk(st0[6], st0[7]);
        int a2 = cvtpk(st0[8], st0[9]),   b2 = cvtpk(st0[12], st0[13]);
        int a3 = cvtpk(st0[10], st0[11]), b3 = cvtpk(st0[14], st0[15]);
        int a4 = cvtpk(st1[0], st1[1]),   b4 = cvtpk(st1[4], st1[5]);
        int a5 = cvtpk(st1[2], st1[3]),   b5 = cvtpk(st1[6], st1[7]);
        int a6 = cvtpk(st1[8], st1[9]),   b6 = cvtpk(st1[12], st1[13]);
        int a7 = cvtpk(st1[10], st1[11]), b7 = cvtpk(st1[14], st1[15]);
        asm volatile("v_permlane32_swap_b32 %0, %1" : "+v"(a0), "+v"(b0));
        asm volatile("v_permlane32_swap_b32 %0, %1" : "+v"(a1), "+v"(b1));
        asm volatile("v_permlane32_swap_b32 %0, %1" : "+v"(a2), "+v"(b2));
        asm volatile("v_permlane32_swap_b32 %0, %1" : "+v"(a3), "+v"(b3));
        asm volatile("v_permlane32_swap_b32 %0, %1" : "+v"(a4), "+v"(b4));
        asm volatile("v_permlane32_swap_b32 %0, %1" : "+v"(a5), "+v"(b5));
        asm volatile("v_permlane32_swap_b32 %0, %1" : "+v"(a6), "+v"(b6));
        asm volatile("v_permlane32_swap_b32 %0, %1" : "+v"(a7), "+v"(b7));
        i32x4 pw0 = {a0, a1, b0, b1}; s16x8 pa0 = *(s16x8*)&pw0;
        i32x4 pw1 = {a2, a3, b2, b3}; s16x8 pa1 = *(s16x8*)&pw1;
        i32x4 pw2 = {a4, a5, b4, b5}; s16x8 pa2 = *(s16x8*)&pw2;
        i32x4 pw3 = {a6, a7, b6, b7}; s16x8 pa3 = *(s16x8*)&pw3;

        // ---- PV: o[nt] += P(32x64) * V(64 x 32d-tile)
        __builtin_amdgcn_s_setprio(1);
        #define PV_NT(oo, nt) { \
            const int vr = (nt) * 32 + l31; \
            const int vsw = (vr & 7) << 4; \
            const char* vb = smem + 16384 + vr * 128; \
            oo = __builtin_amdgcn_mfma_f32_32x32x16_bf16(pa0, *(const s16x8*)(vb + ((0  + hi16) ^ vsw)), oo, 0, 0, 0); \
            oo = __builtin_amdgcn_mfma_f32_32x32x16_bf16(pa1, *(const s16x8*)(vb + ((32 + hi16) ^ vsw)), oo, 0, 0, 0); \
            oo = __builtin_amdgcn_mfma_f32_32x32x16_bf16(pa2, *(const s16x8*)(vb + ((64 + hi16) ^ vsw)), oo, 0, 0, 0); \
            oo = __builtin_amdgcn_mfma_f32_32x32x16_bf16(pa3, *(const s16x8*)(vb + ((96 + hi16) ^ vsw)), oo, 0, 0, 0); }
        PV_NT(o0, 0) PV_NT(o1, 1) PV_NT(o2, 2) PV_NT(o3, 3)
        #undef PV_NT
        __builtin_amdgcn_s_setprio(0);

        if (j + 1 < nj) {
            __syncthreads();
            #pragma unroll
            for (int p = 0; p < 4; ++p) {
                int r0 = krow + p * 16;
                *(s16x8*)(smem + r0 * 256 + ((kch * 16) ^ ((r0 & 7) << 4))) = kst[p];
                int d0 = vdr + p * 32;
                *(s16x8*)(smem + 16384 + d0 * 128 + ((vch * 16) ^ ((d0 & 7) << 4))) = vst[p];
            }
            __syncthreads();
        }
    }

    // ---- epilogue: repack O via LDS, then coalesced dwordx4 stores
    __syncthreads();                              // all waves done reading K/V LDS
    short* os = (short*)smem;                     // reuse as [128 q][128 d] bf16
    #define STORE_NT(oo, nt) { \
        _Pragma("unroll") \
        for (int r = 0; r < 16; ++r) { \
            int qin = w * 32 + (r & 3) + 8 * (r >> 2) + 4 * hi; \
            os[qin * 128 + (nt) * 32 + l31] = (short)f2bf(oo[r]); \
        } }
    STORE_NT(o0, 0) STORE_NT(o1, 1) STORE_NT(o2, 2) STORE_NT(o3, 3)
    #undef STORE_NT
    // each wave reads back its OWN 32 rows (no cross-wave barrier needed)
    unsigned short* pob = po + (size_t)slot * 16384 + w * 4096;
    const short* osw = os + w * 4096;
    #pragma unroll
    for (int jj = 0; jj < 8; ++jj) {
        s16x8 v = *(const s16x8*)(osw + jj * 512 + lane * 8);
        *(s16x8*)(pob + jj * 512 + lane * 8) = v;
    }
    if (lane < 32) {
        float* pm = pml + (size_t)slot * 256 + (w * 32 + lane) * 2;
        pm[0] = m_run; pm[1] = l_run;
    }
}

// ---- combine partials: out[q][:] = sum_c w_c*O_c / sum_c w_c*l_c
__global__ __launch_bounds__(256) void combine_kernel(const unsigned short* __restrict__ po,
                                                      const float* __restrict__ pml,
                                                      float* __restrict__ out) {
    const int tid = threadIdx.x;
    const int row = blockIdx.x * 8 + (tid >> 5);
    const int l32 = tid & 31;
    const int b = row >> 12, q = row & 4095;
    const int qt = q >> 7, qr = q & 127;
    const int nc = (q >> 8) + 1;
    const int cum = ((qt >> 1) + (qt & 1)) * ((qt >> 1) + 1);
    const size_t bslot = (size_t)b * 272 + cum;

    float M = -1e30f;
    for (int cc = 0; cc < nc; ++cc)
        M = fmaxf(M, pml[(bslot + cc) * 256 + qr * 2]);
    float L = 0.f;
    f32x4 acc = {0.f, 0.f, 0.f, 0.f};
    for (int cc = 0; cc < nc; ++cc) {
        const float* pm = pml + (bslot + cc) * 256 + qr * 2;
        float wgt = exp2f(pm[0] - M);
        L += wgt * pm[1];
        u16x4 x = *(const u16x4*)(po + (bslot + cc) * 16384 + qr * 128 + l32 * 4);
        #pragma unroll
        for (int e = 0; e < 4; ++e) {
            union { unsigned u; float f; } cv; cv.u = ((unsigned)x[e]) << 16;
            acc[e] += wgt * cv.f;
        }
    }
    float inv = 1.f / L;
    f32x4 y = {acc[0] * inv, acc[1] * inv, acc[2] * inv, acc[3] * inv};
    *(f32x4*)(out + (size_t)row * HEAD + l32 * 4) = y;
}

extern "C" void kernel_launch(void* const* d_in, const int* in_sizes, int n_in,
                              void* d_out, int out_size, void* d_ws, size_t ws_size,
                              hipStream_t stream) {
    const float* ctx = (const float*)d_in[0];
    const float* Wk  = (const float*)d_in[1];
    const float* Wq  = (const float*)d_in[2];
    const float* Wv  = (const float*)d_in[3];
    float* out = (float*)d_out;

    // ws (shorts): Wt[393216] | Q | K | Vt (2097152 each) | po u16[1088*16384] | pml f32
    unsigned short* Wt  = (unsigned short*)d_ws;
    unsigned short* Qb  = Wt + 3 * 131072;
    unsigned short* Kb  = Qb + 2097152;
    unsigned short* Vtb = Kb + 2097152;
    unsigned short* po  = Vtb + 2097152;
    float* pml = (float*)(po + (size_t)1088 * 16384);

    wt_kernel<<<48, 256, 0, stream>>>(Wq, Wk, Wv, Wt);
    proj_kernel<<<dim3(256, 3), 256, 0, stream>>>(ctx, Wt, Qb, Kb, Vtb);
    attn_kernel<<<1088, 256, 0, stream>>>(Qb, Kb, Vtb, po, pml);
    combine_kernel<<<2048, 256, 0, stream>>>(po, pml, out);
}